// Round 1
// baseline (1810.851 us; speedup 1.0000x reference)
//
#include <hip/hip_runtime.h>

#define NBATCH 2048
#define NS 200
#define NDIN 64
#define NK 8
#define ND 64
#define NITERS 50

// LDS float offsets. The IN region (v staging) is reused during the
// iteration loop for eS / zn / z-partials / scalars (v lives in registers).
#define IN_OFF 0
#define IN_LD 64
#define BT_OFF 12800   // b-state, transposed [K][208]
#define BT_LD 208
#define ES_OFF 0       // e[s][k] : [200][8]
#define ZN_OFF 1664    // zn[k][d]: [8][68]
#define ZP_OFF 2208    // z partials per wave: [4][8][68]
#define SE_OFF 4384    // sum_e[k]: [8]
#define CC_OFF 4392    // c[k]    : [8]
#define SMEM_FLOATS 14464

__device__ __forceinline__ float4 f4fma(float a, float4 x, float4 c) {
  c.x = fmaf(a, x.x, c.x);
  c.y = fmaf(a, x.y, c.y);
  c.z = fmaf(a, x.z, c.z);
  c.w = fmaf(a, x.w, c.w);
  return c;
}

__global__ __launch_bounds__(256, 2) void mie_kernel(
    const float* __restrict__ gin, const float* __restrict__ gW,
    const float* __restrict__ gbias, const float* __restrict__ gb0,
    float* __restrict__ gout) {
  __shared__ float sm[SMEM_FLOATS];
  const int b = blockIdx.x;
  const int tid = threadIdx.x;
  const int d4 = tid & 15;   // d-quad index (z phase)
  const int sp = tid >> 4;   // s-partition (z phase)
  const int kg = tid >> 5;   // interest group (softmax phase)
  const int l32 = tid & 31;
  const int wv = tid >> 6;   // wave id

  // ---- stage inputs [200][64] (linear) ----
  const float4* gin4 =
      reinterpret_cast<const float4*>(gin) + (size_t)b * (NS * NDIN / 4);
  for (int idx = tid; idx < NS * NDIN / 4; idx += 256)
    *reinterpret_cast<float4*>(&sm[IN_OFF + idx * 4]) = gin4[idx];

  // ---- stage b_init -> bT[k][s] ----
  const float* gb = gb0 + (size_t)b * (NS * NK);
  for (int idx = tid; idx < NS * NK; idx += 256)
    sm[BT_OFF + (idx & 7) * BT_LD + (idx >> 3)] = gb[idx];
  __syncthreads();

  // ---- v = inputs @ W + bias, into B-layout registers ----
  // thread (d4, sp) owns rows s = sp + 16j (j<13), cols d4*4..d4*4+3
  const float4* gW4 = reinterpret_cast<const float4*>(gW);
  float4 bias4 = reinterpret_cast<const float4*>(gbias)[d4];
  float4 vB[13];
#pragma unroll
  for (int j = 0; j < 13; ++j) vB[j] = bias4;
#pragma unroll 1
  for (int q = 0; q < 16; ++q) {
    const float4* wr = gW4 + q * 64 + d4;  // W rows 4q..4q+3, quad d4
    float4 w0 = wr[0], w1 = wr[16], w2 = wr[32], w3 = wr[48];
#pragma unroll
    for (int j = 0; j < 13; ++j) {
      int s = sp + 16 * j;
      if (s < NS) {
        float4 a4 =
            *reinterpret_cast<const float4*>(&sm[IN_OFF + s * IN_LD + q * 4]);
        vB[j] = f4fma(a4.x, w0, vB[j]);
        vB[j] = f4fma(a4.y, w1, vB[j]);
        vB[j] = f4fma(a4.z, w2, vB[j]);
        vB[j] = f4fma(a4.w, w3, vB[j]);
      }
    }
  }
  __syncthreads();
  // write v back over the input region, then load C-layout registers
#pragma unroll
  for (int j = 0; j < 13; ++j) {
    int s = sp + 16 * j;
    if (s < NS)
      *reinterpret_cast<float4*>(&sm[IN_OFF + s * IN_LD + d4 * 4]) = vB[j];
  }
  __syncthreads();
  float4 vC[16];
  if (tid < NS) {
#pragma unroll
    for (int q = 0; q < 16; ++q)
      vC[q] =
          *reinterpret_cast<const float4*>(&sm[IN_OFF + tid * IN_LD + q * 4]);
  }
  __syncthreads();  // IN region now dead -> reused as eS/zn/zp

  for (int iter = 0; iter < NITERS; ++iter) {
    // ---- A: e = exp(b - max), S_e (8 groups of 32 lanes, one per k) ----
    float bv[7];
    float mx = -3.0e38f;
#pragma unroll
    for (int jj = 0; jj < 7; ++jj) {
      int s = l32 + 32 * jj;
      bv[jj] = (s < NS) ? sm[BT_OFF + kg * BT_LD + s] : -3.0e38f;
      mx = fmaxf(mx, bv[jj]);
    }
    mx = fmaxf(mx, __shfl_xor(mx, 1, 64));
    mx = fmaxf(mx, __shfl_xor(mx, 2, 64));
    mx = fmaxf(mx, __shfl_xor(mx, 4, 64));
    mx = fmaxf(mx, __shfl_xor(mx, 8, 64));
    mx = fmaxf(mx, __shfl_xor(mx, 16, 64));
    float sum = 0.f;
#pragma unroll
    for (int jj = 0; jj < 7; ++jj) {
      int s = l32 + 32 * jj;
      if (s < NS) {
        float e = __expf(bv[jj] - mx);
        sm[ES_OFF + s * 8 + kg] = e;
        sum += e;
      }
    }
    sum += __shfl_xor(sum, 1, 64);
    sum += __shfl_xor(sum, 2, 64);
    sum += __shfl_xor(sum, 4, 64);
    sum += __shfl_xor(sum, 8, 64);
    sum += __shfl_xor(sum, 16, 64);
    if (l32 == 0) sm[SE_OFF + kg] = sum;
    __syncthreads();

    // ---- B: zn[k][d] = sum_s e[s][k] * v[s][d] ----
    float4 za[8];
#pragma unroll
    for (int k = 0; k < 8; ++k) za[k] = make_float4(0.f, 0.f, 0.f, 0.f);
#pragma unroll
    for (int j = 0; j < 13; ++j) {
      int s = sp + 16 * j;
      if (s < NS) {
        float4 e0 = *reinterpret_cast<const float4*>(&sm[ES_OFF + s * 8]);
        float4 e1 = *reinterpret_cast<const float4*>(&sm[ES_OFF + s * 8 + 4]);
        float4 v4 = vB[j];
        za[0] = f4fma(e0.x, v4, za[0]);
        za[1] = f4fma(e0.y, v4, za[1]);
        za[2] = f4fma(e0.z, v4, za[2]);
        za[3] = f4fma(e0.w, v4, za[3]);
        za[4] = f4fma(e1.x, v4, za[4]);
        za[5] = f4fma(e1.y, v4, za[5]);
        za[6] = f4fma(e1.z, v4, za[6]);
        za[7] = f4fma(e1.w, v4, za[7]);
      }
    }
    // reduce the wave's 4 s-partitions (lanes ±16, ±32)
#pragma unroll
    for (int k = 0; k < 8; ++k) {
      za[k].x += __shfl_xor(za[k].x, 16, 64);
      za[k].y += __shfl_xor(za[k].y, 16, 64);
      za[k].z += __shfl_xor(za[k].z, 16, 64);
      za[k].w += __shfl_xor(za[k].w, 16, 64);
      za[k].x += __shfl_xor(za[k].x, 32, 64);
      za[k].y += __shfl_xor(za[k].y, 32, 64);
      za[k].z += __shfl_xor(za[k].z, 32, 64);
      za[k].w += __shfl_xor(za[k].w, 32, 64);
    }
    if ((tid & 63) < 16) {
#pragma unroll
      for (int k = 0; k < 8; ++k)
        *reinterpret_cast<float4*>(&sm[ZP_OFF + wv * 544 + k * 68 + d4 * 4]) =
            za[k];
    }
    __syncthreads();

    // ---- B2: cross-wave reduce, squash scalars, (final: output) ----
    if (tid < 128) {
      int kk = tid >> 4, dq = tid & 15;
      float4 p0 = *reinterpret_cast<const float4*>(
          &sm[ZP_OFF + 0 * 544 + kk * 68 + dq * 4]);
      float4 p1 = *reinterpret_cast<const float4*>(
          &sm[ZP_OFF + 1 * 544 + kk * 68 + dq * 4]);
      float4 p2 = *reinterpret_cast<const float4*>(
          &sm[ZP_OFF + 2 * 544 + kk * 68 + dq * 4]);
      float4 p3 = *reinterpret_cast<const float4*>(
          &sm[ZP_OFF + 3 * 544 + kk * 68 + dq * 4]);
      float4 zn4;
      zn4.x = p0.x + p1.x + p2.x + p3.x;
      zn4.y = p0.y + p1.y + p2.y + p3.y;
      zn4.z = p0.z + p1.z + p2.z + p3.z;
      zn4.w = p0.w + p1.w + p2.w + p3.w;
      *reinterpret_cast<float4*>(&sm[ZN_OFF + kk * 68 + dq * 4]) = zn4;
      float sq = zn4.x * zn4.x + zn4.y * zn4.y + zn4.z * zn4.z + zn4.w * zn4.w;
      sq += __shfl_xor(sq, 1, 64);
      sq += __shfl_xor(sq, 2, 64);
      sq += __shfl_xor(sq, 4, 64);
      sq += __shfl_xor(sq, 8, 64);
      float Se = sm[SE_OFF + kk];
      float ns = sq / (64.f * Se * Se);  // mean_d z^2, z = zn/Se
      float g = ns / ((1.f + ns) * sqrtf(ns + 1e-9f));
      float cv = g / Se;  // u = cv * zn
      if (dq == 0) sm[CC_OFF + kk] = cv;
      if (iter == NITERS - 1) {
        float4 u4;
        u4.x = cv * zn4.x;
        u4.y = cv * zn4.y;
        u4.z = cv * zn4.z;
        u4.w = cv * zn4.w;
        *reinterpret_cast<float4*>(
            &gout[(size_t)b * (NK * ND) + kk * 64 + dq * 4]) = u4;
      }
    }
    __syncthreads();

    // ---- C: b[s][k] += c[k] * (v[s,:] . zn[k,:]) ----
    if (iter < NITERS - 1 && tid < NS) {
#pragma unroll 2
      for (int k = 0; k < 8; ++k) {
        float a = 0.f;
#pragma unroll
        for (int q = 0; q < 16; ++q) {
          float4 z4 =
              *reinterpret_cast<const float4*>(&sm[ZN_OFF + k * 68 + q * 4]);
          float4 v4 = vC[q];
          a = fmaf(v4.x, z4.x, a);
          a = fmaf(v4.y, z4.y, a);
          a = fmaf(v4.z, z4.z, a);
          a = fmaf(v4.w, z4.w, a);
        }
        sm[BT_OFF + k * BT_LD + tid] += sm[CC_OFF + k] * a;
      }
    }
    __syncthreads();
  }
}

extern "C" void kernel_launch(void* const* d_in, const int* in_sizes, int n_in,
                              void* d_out, int out_size, void* d_ws,
                              size_t ws_size, hipStream_t stream) {
  const float* gin = (const float*)d_in[0];
  const float* gW = (const float*)d_in[1];
  const float* gbias = (const float*)d_in[2];
  const float* gb0 = (const float*)d_in[3];
  float* gout = (float*)d_out;
  hipLaunchKernelGGL(mie_kernel, dim3(NBATCH), dim3(256), 0, stream, gin, gW,
                     gbias, gb0, gout);
}

// Round 5
// 699.035 us; speedup vs baseline: 2.5905x; 2.5905x over previous
//
#include <hip/hip_runtime.h>

#define NITERS 50

typedef __attribute__((ext_vector_type(4))) float f32x4;
typedef __attribute__((ext_vector_type(8))) _Float16 f16x8;
typedef __attribute__((ext_vector_type(4))) _Float16 f16x4;

// ---- LDS: one 57600-byte arena (28800 shorts) ----
// setup phase:  stage_h = halves [0,14400)      v_hi[200][72]
//               stage_l = halves [14400,28800)  v_lo[200][72]
// steady state (overlays stage after fragments are in registers):
//   bT   f32 [8][204]        floats [0,1632)
//   Se   f32 [8]             floats [1632,1640)
//   sqp  f32 [4][8]          floats [1640,1672)
//   eF_h halves [7][4][8][8] halves [3360,5152)   e hi-limbs, frag-ready
//   eF_l halves [5152,6944)
//   znF_h halves [2][4][8][8] halves [6944,7456)
//   znF_l halves [7456,7968)
#define SE_F 1632
#define SQP_F 1640
#define EFH_H 3360
#define EFL_H 5152
#define ZNH_H 6944
#define ZNL_H 7456

struct HL {
  _Float16 h, l;
};
__device__ __forceinline__ HL split2(float x) {
  HL r;
  r.h = (_Float16)x;
  r.l = (_Float16)(x - (float)r.h);
  return r;
}

__global__ __launch_bounds__(256, 2) void mie3(
    const float* __restrict__ gin, const float* __restrict__ gW,
    const float* __restrict__ gbias, const float* __restrict__ gb0,
    float* __restrict__ gout) {
  __shared__ short smem[28800];
  float* smF = (float*)smem;
  _Float16* smH = (_Float16*)smem;
  _Float16* sth = smH;           // v hi staging
  _Float16* stl = smH + 14400;   // v lo staging

  const int b = blockIdx.x;
  const int tid = threadIdx.x;
  const int wv = tid >> 6;
  const int lane = tid & 63;
  const int col = lane & 15;
  const int oct = lane >> 4;
  const int kcol = col & 7;
  const int d0 = wv * 16;

  // ================= setup: v = in @ W + bias (fp16 2-limb, 3-product) ===
  f16x8 wh[2], wl[2];
#pragma unroll
  for (int c = 0; c < 2; ++c)
#pragma unroll
    for (int j = 0; j < 8; ++j) {
      HL t = split2(gW[(32 * c + oct * 8 + j) * 64 + d0 + col]);
      wh[c][j] = t.h;
      wl[c][j] = t.l;
    }
  float biasc = gbias[d0 + col];
  const float* ginb = gin + (size_t)b * 12800;

#pragma unroll 1
  for (int mt = 0; mt < 13; ++mt) {
    int sa = mt * 16 + col;
    f16x8 ah[2] = {{}, {}}, al[2] = {{}, {}};
    if (sa < 200) {
#pragma unroll
      for (int c = 0; c < 2; ++c) {
        const float* p = ginb + sa * 64 + 32 * c + oct * 8;
        float4 x0 = *(const float4*)p;
        float4 x1 = *(const float4*)(p + 4);
        HL t0 = split2(x0.x), t1 = split2(x0.y), t2 = split2(x0.z),
           t3 = split2(x0.w);
        HL t4 = split2(x1.x), t5 = split2(x1.y), t6 = split2(x1.z),
           t7 = split2(x1.w);
        ah[c][0] = t0.h; al[c][0] = t0.l;
        ah[c][1] = t1.h; al[c][1] = t1.l;
        ah[c][2] = t2.h; al[c][2] = t2.l;
        ah[c][3] = t3.h; al[c][3] = t3.l;
        ah[c][4] = t4.h; al[c][4] = t4.l;
        ah[c][5] = t5.h; al[c][5] = t5.l;
        ah[c][6] = t6.h; al[c][6] = t6.l;
        ah[c][7] = t7.h; al[c][7] = t7.l;
      }
    }
    f32x4 acc = {0.f, 0.f, 0.f, 0.f};
#pragma unroll
    for (int c = 0; c < 2; ++c) {
      acc = __builtin_amdgcn_mfma_f32_16x16x32_f16(ah[c], wh[c], acc, 0, 0, 0);
      acc = __builtin_amdgcn_mfma_f32_16x16x32_f16(ah[c], wl[c], acc, 0, 0, 0);
      acc = __builtin_amdgcn_mfma_f32_16x16x32_f16(al[c], wh[c], acc, 0, 0, 0);
    }
#pragma unroll
    for (int r = 0; r < 4; ++r) {
      int so = mt * 16 + oct * 4 + r;
      if (so < 200) {
        HL t = split2(acc[r] + biasc);
        sth[so * 72 + d0 + col] = t.h;
        stl[so * 72 + d0 + col] = t.l;
      }
    }
  }
  __syncthreads();

  // ---- load persistent v fragments into registers ----
  // vB (phase-B A-operand, vT orientation): lane needs v[32t+oct*8+j][d0+col]
  f16x8 vBh[7], vBl[7];
#pragma unroll
  for (int t = 0; t < 7; ++t) {
    if (t < 6 || oct == 0) {
#pragma unroll
      for (int j = 0; j < 8; ++j) {
        int sR = 32 * t + oct * 8 + j;
        vBh[t][j] = sth[sR * 72 + d0 + col];
        vBl[t][j] = stl[sR * 72 + d0 + col];
      }
    } else {
      vBh[t] = f16x8{};
      vBl[t] = f16x8{};
    }
  }
  // vC (phase-C A-operand, row orientation): lane needs v[16mt+col][32c+oct*8..+7]
  f16x8 vCh[4][2], vCl[4][2];
#pragma unroll
  for (int u = 0; u < 4; ++u) {
    int mt = wv + 4 * u;
    if (mt < 13) {
      int sR = mt * 16 + col;
      if (sR > 199) sR = 199;  // dup rows feed unstored D rows only
#pragma unroll
      for (int c = 0; c < 2; ++c) {
        vCh[u][c] = *(const f16x8*)&sth[sR * 72 + 32 * c + oct * 8];
        vCl[u][c] = *(const f16x8*)&stl[sR * 72 + 32 * c + oct * 8];
      }
    } else {
#pragma unroll
      for (int c = 0; c < 2; ++c) {
        vCh[u][c] = f16x8{};
        vCl[u][c] = f16x8{};
      }
    }
  }
  __syncthreads();

  // ---- stage b_init -> bT[k][s] fp32 (overwrites dead v staging) ----
  const float* gb = gb0 + (size_t)b * 1600;
  for (int idx = tid; idx < 1600; idx += 256)
    smF[(idx & 7) * 204 + (idx >> 3)] = gb[idx];
  __syncthreads();

  // ================= routing iterations =================
#pragma unroll 1
  for (int it = 0; it < NITERS; ++it) {
    // ---- Phase A: e' = 4096*exp(b-max) as fp16 2-limb, frag-ready; Se ----
#pragma unroll
    for (int ki = 0; ki < 2; ++ki) {
      int kk = 2 * wv + ki;
      float4 bv;
      if (lane < 50)
        bv = *(const float4*)&smF[kk * 204 + 4 * lane];
      else
        bv = make_float4(-3e38f, -3e38f, -3e38f, -3e38f);
      float mx = fmaxf(fmaxf(bv.x, bv.y), fmaxf(bv.z, bv.w));
#pragma unroll
      for (int m = 1; m <= 32; m <<= 1) mx = fmaxf(mx, __shfl_xor(mx, m, 64));
      float e0 = 0.f, e1 = 0.f, e2 = 0.f, e3 = 0.f;
      if (lane < 50) {
        e0 = __expf(bv.x - mx) * 4096.f;
        e1 = __expf(bv.y - mx) * 4096.f;
        e2 = __expf(bv.z - mx) * 4096.f;
        e3 = __expf(bv.w - mx) * 4096.f;
      }
      HL s0 = split2(e0), s1 = split2(e1), s2 = split2(e2), s3 = split2(e3);
      f16x4 hv, lv;
      hv[0] = s0.h; lv[0] = s0.l;
      hv[1] = s1.h; lv[1] = s1.l;
      hv[2] = s2.h; lv[2] = s2.l;
      hv[3] = s3.h; lv[3] = s3.l;
      if (lane < 56) {
        int slot = (((lane >> 3) * 4 + ((lane >> 1) & 3)) * 8 + kk) * 8 +
                   (lane & 1) * 4;
        *(f16x4*)&smH[EFH_H + slot] = hv;
        *(f16x4*)&smH[EFL_H + slot] = lv;
      }
      float se = ((float)hv[0] + (float)lv[0]) + ((float)hv[1] + (float)lv[1]) +
                 ((float)hv[2] + (float)lv[2]) + ((float)hv[3] + (float)lv[3]);
#pragma unroll
      for (int m = 1; m <= 32; m <<= 1) se += __shfl_xor(se, m, 64);
      if (lane == 0) smF[SE_F + kk] = se;
    }
    __syncthreads();

    // ---- Phase B: zn^T[d][k] = sum_s v[s][d]*e'[k][s]  (3-product) ----
    f32x4 z = {0.f, 0.f, 0.f, 0.f};
#pragma unroll
    for (int t = 0; t < 7; ++t) {
      f16x8 eh = *(const f16x8*)&smH[EFH_H + ((t * 4 + oct) * 8 + kcol) * 8];
      f16x8 el = *(const f16x8*)&smH[EFL_H + ((t * 4 + oct) * 8 + kcol) * 8];
      z = __builtin_amdgcn_mfma_f32_16x16x32_f16(vBh[t], eh, z, 0, 0, 0);
      z = __builtin_amdgcn_mfma_f32_16x16x32_f16(vBh[t], el, z, 0, 0, 0);
      z = __builtin_amdgcn_mfma_f32_16x16x32_f16(vBl[t], eh, z, 0, 0, 0);
    }
    float sq = z[0] * z[0] + z[1] * z[1] + z[2] * z[2] + z[3] * z[3];
    sq += __shfl_xor(sq, 16, 64);
    sq += __shfl_xor(sq, 32, 64);
    if (oct == 0 && col < 8) smF[SQP_F + wv * 8 + col] = sq;
    if (col < 8) {
#pragma unroll
      for (int r = 0; r < 4; ++r) {
        int d = d0 + oct * 4 + r;
        HL t = split2(z[r] * (1.f / 4096.f));
        int slot = (((d >> 5) * 4 + ((d >> 3) & 3)) * 8 + col) * 8 + (d & 7);
        smH[ZNH_H + slot] = t.h;
        smH[ZNL_H + slot] = t.l;
      }
    }
    __syncthreads();

    // ---- squash scalars (computed redundantly per lane for k = kcol) ----
    float sqt = smF[SQP_F + kcol] + smF[SQP_F + 8 + kcol] +
                smF[SQP_F + 16 + kcol] + smF[SQP_F + 24 + kcol];
    float Se = smF[SE_F + kcol];
    float ns = sqt / (64.f * Se * Se);
    float g = ns / ((1.f + ns) * sqrtf(ns + 1e-9f));
    float cv = g / Se;  // u[k][d] = cv * z  (z is 4096*zn_raw, cv = g/(4096*Se_raw))

    if (it == NITERS - 1) {
      if (col < 8) {
#pragma unroll
        for (int r = 0; r < 4; ++r)
          gout[(size_t)b * 512 + col * 64 + d0 + oct * 4 + r] = cv * z[r];
      }
    } else {
      // ---- Phase C: bT[k][s] += cvC * sum_d v[s][d]*zn[k][d] ----
      float cvC = cv * 4096.f;
      f16x8 zh[2], zl[2];
#pragma unroll
      for (int c = 0; c < 2; ++c) {
        zh[c] = *(const f16x8*)&smH[ZNH_H + ((c * 4 + oct) * 8 + kcol) * 8];
        zl[c] = *(const f16x8*)&smH[ZNL_H + ((c * 4 + oct) * 8 + kcol) * 8];
      }
#pragma unroll
      for (int u = 0; u < 4; ++u) {
        int mt = wv + 4 * u;
        if (mt < 13) {
          f32x4 a = {0.f, 0.f, 0.f, 0.f};
#pragma unroll
          for (int c = 0; c < 2; ++c) {
            a = __builtin_amdgcn_mfma_f32_16x16x32_f16(vCh[u][c], zh[c], a, 0, 0, 0);
            a = __builtin_amdgcn_mfma_f32_16x16x32_f16(vCh[u][c], zl[c], a, 0, 0, 0);
            a = __builtin_amdgcn_mfma_f32_16x16x32_f16(vCl[u][c], zh[c], a, 0, 0, 0);
          }
          if (col < 8) {
#pragma unroll
            for (int r = 0; r < 4; ++r) {
              int s = mt * 16 + oct * 4 + r;
              if (s < 200) smF[col * 204 + s] += cvC * a[r];
            }
          }
        }
      }
    }
    __syncthreads();
  }
}

extern "C" void kernel_launch(void* const* d_in, const int* in_sizes, int n_in,
                              void* d_out, int out_size, void* d_ws,
                              size_t ws_size, hipStream_t stream) {
  const float* gin = (const float*)d_in[0];
  const float* gW = (const float*)d_in[1];
  const float* gbias = (const float*)d_in[2];
  const float* gb0 = (const float*)d_in[3];
  float* gout = (float*)d_out;
  hipLaunchKernelGGL(mie3, dim3(2048), dim3(256), 0, stream, gin, gW, gbias,
                     gb0, gout);
}

// Round 6
// 698.675 us; speedup vs baseline: 2.5918x; 1.0005x over previous
//
#include <hip/hip_runtime.h>

#define NITERS 50

typedef __attribute__((ext_vector_type(4))) float f32x4;
typedef __attribute__((ext_vector_type(8))) _Float16 f16x8;
typedef __attribute__((ext_vector_type(4))) _Float16 f16x4;

// ---- LDS: one 57600-byte arena (28800 shorts) ----
// setup phase:  stage_h = halves [0,14400)      v_hi[200][72]
//               stage_l = halves [14400,28800)  v_lo[200][72]
// steady state (overlays stage after fragments are in registers):
//   bT   f32 [8][204]        floats [0,1632)
//   Se   f32 [8]             floats [1632,1640)
//   sqp  f32 [4][8]          floats [1640,1672)
//   eF_h halves [7][4][8][8] halves [3360,5152)   e hi-limbs, frag-ready
//   eF_l halves [5152,6944)
//   znF_h halves [2][4][8][8] halves [6944,7456)
//   znF_l halves [7456,7968)
#define SE_F 1632
#define SQP_F 1640
#define EFH_H 3360
#define EFL_H 5152
#define ZNH_H 6944
#define ZNL_H 7456

struct HL {
  _Float16 h, l;
};
__device__ __forceinline__ HL split2(float x) {
  HL r;
  r.h = (_Float16)x;
  r.l = (_Float16)(x - (float)r.h);
  return r;
}

__global__ __launch_bounds__(256, 2) void mie3(
    const float* __restrict__ gin, const float* __restrict__ gW,
    const float* __restrict__ gbias, const float* __restrict__ gb0,
    float* __restrict__ gout) {
  __shared__ short smem[28800];
  float* smF = (float*)smem;
  _Float16* smH = (_Float16*)smem;
  _Float16* sth = smH;           // v hi staging
  _Float16* stl = smH + 14400;   // v lo staging

  const int b = blockIdx.x;
  const int tid = threadIdx.x;
  const int wv = tid >> 6;
  const int lane = tid & 63;
  const int col = lane & 15;
  const int oct = lane >> 4;
  const int kcol = col & 7;
  const int d0 = wv * 16;

  // ================= setup: v = in @ W + bias (fp16 2-limb, 3-product) ===
  f16x8 wh[2], wl[2];
#pragma unroll
  for (int c = 0; c < 2; ++c)
#pragma unroll
    for (int j = 0; j < 8; ++j) {
      HL t = split2(gW[(32 * c + oct * 8 + j) * 64 + d0 + col]);
      wh[c][j] = t.h;
      wl[c][j] = t.l;
    }
  float biasc = gbias[d0 + col];
  const float* ginb = gin + (size_t)b * 12800;

#pragma unroll 1
  for (int mt = 0; mt < 13; ++mt) {
    int sa = mt * 16 + col;
    f16x8 ah[2] = {{}, {}}, al[2] = {{}, {}};
    if (sa < 200) {
#pragma unroll
      for (int c = 0; c < 2; ++c) {
        const float* p = ginb + sa * 64 + 32 * c + oct * 8;
        float4 x0 = *(const float4*)p;
        float4 x1 = *(const float4*)(p + 4);
        HL t0 = split2(x0.x), t1 = split2(x0.y), t2 = split2(x0.z),
           t3 = split2(x0.w);
        HL t4 = split2(x1.x), t5 = split2(x1.y), t6 = split2(x1.z),
           t7 = split2(x1.w);
        ah[c][0] = t0.h; al[c][0] = t0.l;
        ah[c][1] = t1.h; al[c][1] = t1.l;
        ah[c][2] = t2.h; al[c][2] = t2.l;
        ah[c][3] = t3.h; al[c][3] = t3.l;
        ah[c][4] = t4.h; al[c][4] = t4.l;
        ah[c][5] = t5.h; al[c][5] = t5.l;
        ah[c][6] = t6.h; al[c][6] = t6.l;
        ah[c][7] = t7.h; al[c][7] = t7.l;
      }
    }
    f32x4 acc = {0.f, 0.f, 0.f, 0.f};
#pragma unroll
    for (int c = 0; c < 2; ++c) {
      acc = __builtin_amdgcn_mfma_f32_16x16x32_f16(ah[c], wh[c], acc, 0, 0, 0);
      acc = __builtin_amdgcn_mfma_f32_16x16x32_f16(ah[c], wl[c], acc, 0, 0, 0);
      acc = __builtin_amdgcn_mfma_f32_16x16x32_f16(al[c], wh[c], acc, 0, 0, 0);
    }
#pragma unroll
    for (int r = 0; r < 4; ++r) {
      int so = mt * 16 + oct * 4 + r;
      if (so < 200) {
        HL t = split2(acc[r] + biasc);
        sth[so * 72 + d0 + col] = t.h;
        stl[so * 72 + d0 + col] = t.l;
      }
    }
  }
  __syncthreads();

  // ---- load persistent v fragments into registers ----
  // vB (phase-B A-operand, vT orientation): lane needs v[32t+oct*8+j][d0+col]
  f16x8 vBh[7], vBl[7];
#pragma unroll
  for (int t = 0; t < 7; ++t) {
    if (t < 6 || oct == 0) {
#pragma unroll
      for (int j = 0; j < 8; ++j) {
        int sR = 32 * t + oct * 8 + j;
        vBh[t][j] = sth[sR * 72 + d0 + col];
        vBl[t][j] = stl[sR * 72 + d0 + col];
      }
    } else {
      vBh[t] = f16x8{};
      vBl[t] = f16x8{};
    }
  }
  // vC (phase-C A-operand, row orientation): lane needs v[16mt+col][32c+oct*8..+7]
  f16x8 vCh[4][2], vCl[4][2];
#pragma unroll
  for (int u = 0; u < 4; ++u) {
    int mt = wv + 4 * u;
    if (mt < 13) {
      int sR = mt * 16 + col;
      if (sR > 199) sR = 199;  // dup rows feed unstored D rows only
#pragma unroll
      for (int c = 0; c < 2; ++c) {
        vCh[u][c] = *(const f16x8*)&sth[sR * 72 + 32 * c + oct * 8];
        vCl[u][c] = *(const f16x8*)&stl[sR * 72 + 32 * c + oct * 8];
      }
    } else {
#pragma unroll
      for (int c = 0; c < 2; ++c) {
        vCh[u][c] = f16x8{};
        vCl[u][c] = f16x8{};
      }
    }
  }
  __syncthreads();

  // ---- stage b_init -> bT[k][s] fp32 (overwrites dead v staging) ----
  const float* gb = gb0 + (size_t)b * 1600;
  for (int idx = tid; idx < 1600; idx += 256)
    smF[(idx & 7) * 204 + (idx >> 3)] = gb[idx];
  __syncthreads();

  // ================= routing iterations =================
#pragma unroll 1
  for (int it = 0; it < NITERS; ++it) {
    // ---- Phase A: e' = 4096*exp(b-max) as fp16 2-limb, frag-ready; Se ----
#pragma unroll
    for (int ki = 0; ki < 2; ++ki) {
      int kk = 2 * wv + ki;
      float4 bv;
      if (lane < 50)
        bv = *(const float4*)&smF[kk * 204 + 4 * lane];
      else
        bv = make_float4(-3e38f, -3e38f, -3e38f, -3e38f);
      float mx = fmaxf(fmaxf(bv.x, bv.y), fmaxf(bv.z, bv.w));
#pragma unroll
      for (int m = 1; m <= 32; m <<= 1) mx = fmaxf(mx, __shfl_xor(mx, m, 64));
      float e0 = 0.f, e1 = 0.f, e2 = 0.f, e3 = 0.f;
      if (lane < 50) {
        e0 = __expf(bv.x - mx) * 4096.f;
        e1 = __expf(bv.y - mx) * 4096.f;
        e2 = __expf(bv.z - mx) * 4096.f;
        e3 = __expf(bv.w - mx) * 4096.f;
      }
      HL s0 = split2(e0), s1 = split2(e1), s2 = split2(e2), s3 = split2(e3);
      f16x4 hv, lv;
      hv[0] = s0.h; lv[0] = s0.l;
      hv[1] = s1.h; lv[1] = s1.l;
      hv[2] = s2.h; lv[2] = s2.l;
      hv[3] = s3.h; lv[3] = s3.l;
      if (lane < 56) {
        int slot = (((lane >> 3) * 4 + ((lane >> 1) & 3)) * 8 + kk) * 8 +
                   (lane & 1) * 4;
        *(f16x4*)&smH[EFH_H + slot] = hv;
        *(f16x4*)&smH[EFL_H + slot] = lv;
      }
      float se = ((float)hv[0] + (float)lv[0]) + ((float)hv[1] + (float)lv[1]) +
                 ((float)hv[2] + (float)lv[2]) + ((float)hv[3] + (float)lv[3]);
#pragma unroll
      for (int m = 1; m <= 32; m <<= 1) se += __shfl_xor(se, m, 64);
      if (lane == 0) smF[SE_F + kk] = se;
    }
    __syncthreads();

    // ---- Phase B: zn^T[d][k] = sum_s v[s][d]*e'[k][s]  (3-product) ----
    f32x4 z = {0.f, 0.f, 0.f, 0.f};
#pragma unroll
    for (int t = 0; t < 7; ++t) {
      f16x8 eh = *(const f16x8*)&smH[EFH_H + ((t * 4 + oct) * 8 + kcol) * 8];
      f16x8 el = *(const f16x8*)&smH[EFL_H + ((t * 4 + oct) * 8 + kcol) * 8];
      z = __builtin_amdgcn_mfma_f32_16x16x32_f16(vBh[t], eh, z, 0, 0, 0);
      z = __builtin_amdgcn_mfma_f32_16x16x32_f16(vBh[t], el, z, 0, 0, 0);
      z = __builtin_amdgcn_mfma_f32_16x16x32_f16(vBl[t], eh, z, 0, 0, 0);
    }
    float sq = z[0] * z[0] + z[1] * z[1] + z[2] * z[2] + z[3] * z[3];
    sq += __shfl_xor(sq, 16, 64);
    sq += __shfl_xor(sq, 32, 64);
    if (oct == 0 && col < 8) smF[SQP_F + wv * 8 + col] = sq;
    if (col < 8) {
#pragma unroll
      for (int r = 0; r < 4; ++r) {
        int d = d0 + oct * 4 + r;
        HL t = split2(z[r] * (1.f / 4096.f));
        int slot = (((d >> 5) * 4 + ((d >> 3) & 3)) * 8 + col) * 8 + (d & 7);
        smH[ZNH_H + slot] = t.h;
        smH[ZNL_H + slot] = t.l;
      }
    }
    __syncthreads();

    // ---- squash scalars (computed redundantly per lane for k = kcol) ----
    float sqt = smF[SQP_F + kcol] + smF[SQP_F + 8 + kcol] +
                smF[SQP_F + 16 + kcol] + smF[SQP_F + 24 + kcol];
    float Se = smF[SE_F + kcol];
    float ns = sqt / (64.f * Se * Se);
    float g = ns / ((1.f + ns) * sqrtf(ns + 1e-9f));
    float cv = g / Se;  // u[k][d] = cv * z  (z is 4096*zn_raw, cv = g/(4096*Se_raw))

    if (it == NITERS - 1) {
      if (col < 8) {
#pragma unroll
        for (int r = 0; r < 4; ++r)
          gout[(size_t)b * 512 + col * 64 + d0 + oct * 4 + r] = cv * z[r];
      }
    } else {
      // ---- Phase C: bT[k][s] += cvC * sum_d v[s][d]*zn[k][d] ----
      float cvC = cv * 4096.f;
      f16x8 zh[2], zl[2];
#pragma unroll
      for (int c = 0; c < 2; ++c) {
        zh[c] = *(const f16x8*)&smH[ZNH_H + ((c * 4 + oct) * 8 + kcol) * 8];
        zl[c] = *(const f16x8*)&smH[ZNL_H + ((c * 4 + oct) * 8 + kcol) * 8];
      }
#pragma unroll
      for (int u = 0; u < 4; ++u) {
        int mt = wv + 4 * u;
        if (mt < 13) {
          f32x4 a = {0.f, 0.f, 0.f, 0.f};
#pragma unroll
          for (int c = 0; c < 2; ++c) {
            a = __builtin_amdgcn_mfma_f32_16x16x32_f16(vCh[u][c], zh[c], a, 0, 0, 0);
            a = __builtin_amdgcn_mfma_f32_16x16x32_f16(vCh[u][c], zl[c], a, 0, 0, 0);
            a = __builtin_amdgcn_mfma_f32_16x16x32_f16(vCl[u][c], zh[c], a, 0, 0, 0);
          }
          if (col < 8) {
#pragma unroll
            for (int r = 0; r < 4; ++r) {
              int s = mt * 16 + oct * 4 + r;
              if (s < 200) smF[col * 204 + s] += cvC * a[r];
            }
          }
        }
      }
    }
    __syncthreads();
  }
}

extern "C" void kernel_launch(void* const* d_in, const int* in_sizes, int n_in,
                              void* d_out, int out_size, void* d_ws,
                              size_t ws_size, hipStream_t stream) {
  const float* gin = (const float*)d_in[0];
  const float* gW = (const float*)d_in[1];
  const float* gbias = (const float*)d_in[2];
  const float* gb0 = (const float*)d_in[3];
  float* gout = (float*)d_out;
  hipLaunchKernelGGL(mie3, dim3(2048), dim3(256), 0, stream, gin, gW, gbias,
                     gb0, gout);
}

// Round 7
// 457.214 us; speedup vs baseline: 3.9606x; 1.5281x over previous
//
#include <hip/hip_runtime.h>

#define NITERS 50

typedef __attribute__((ext_vector_type(4))) float f32x4;
typedef __attribute__((ext_vector_type(8))) _Float16 f16x8;
typedef __attribute__((ext_vector_type(4))) _Float16 f16x4;

// ---- LDS: one 36864-byte arena (18432 shorts) ----
// setup (per pass, <=128 rows): sth[row][72] halves [0,9216), stl [9216,18432)
// steady state (after staging passes):
//   bT  f32 [8][204]          floats [0,1632)
//   Se  f32 [8]               floats [1632,1640)
//   sqp f32 [4][8]            floats [1640,1672)
//   eF  halves [28 grp][136]  halves [3400,7208)  N-packed [eh|el], +8 pad/grp
//   znF halves [8 grp][136]   halves [7208,8296)  N-packed [zh|zl]
#define STL_OFF 9216
#define SE_F 1632
#define SQP_F 1640
#define EF_H 3400
#define ZN_H 7208

struct HL {
  _Float16 h, l;
};
__device__ __forceinline__ HL split2(float x) {
  HL r;
  r.h = (_Float16)x;
  r.l = (_Float16)(x - (float)r.h);
  return r;
}

__global__ __launch_bounds__(256, 3) void mie4(
    const float* __restrict__ gin, const float* __restrict__ gW,
    const float* __restrict__ gbias, const float* __restrict__ gb0,
    float* __restrict__ gout) {
  __shared__ short arena[18432];
  float* smF = (float*)arena;
  _Float16* smH = (_Float16*)arena;
  _Float16* sth = smH;
  _Float16* stl = smH + STL_OFF;

  const int b = blockIdx.x;
  const int tid = threadIdx.x;
  const int wv = tid >> 6;
  const int lane = tid & 63;
  const int col = lane & 15;
  const int oct = lane >> 4;
  const int kcol = col & 7;
  const int d0 = wv * 16;

  // ---- W fragments (hi/lo), bias ----
  f16x8 wh[2], wl[2];
#pragma unroll
  for (int c = 0; c < 2; ++c)
#pragma unroll
    for (int j = 0; j < 8; ++j) {
      HL t = split2(gW[(32 * c + oct * 8 + j) * 64 + d0 + col]);
      wh[c][j] = t.h;
      wl[c][j] = t.l;
    }
  float biasc = gbias[d0 + col];
  const float* ginb = gin + (size_t)b * 12800;

  f16x8 vBh[7], vBl[7];
  f16x8 vCh[4][2], vCl[4][2];

  // ---- v = in @ W + bias, staged in two s-passes to halve LDS ----
  auto compute_rows = [&](int mtA, int mtB, int rb) {
#pragma unroll 1
    for (int mt = mtA; mt < mtB; ++mt) {
      int sa = mt * 16 + col;
      f16x8 ah[2] = {{}, {}}, al[2] = {{}, {}};
      if (sa < 200) {
#pragma unroll
        for (int c = 0; c < 2; ++c) {
          const float* p = ginb + sa * 64 + 32 * c + oct * 8;
          float4 x0 = *(const float4*)p;
          float4 x1 = *(const float4*)(p + 4);
          HL t0 = split2(x0.x), t1 = split2(x0.y), t2 = split2(x0.z),
             t3 = split2(x0.w);
          HL t4 = split2(x1.x), t5 = split2(x1.y), t6 = split2(x1.z),
             t7 = split2(x1.w);
          ah[c][0] = t0.h; al[c][0] = t0.l;
          ah[c][1] = t1.h; al[c][1] = t1.l;
          ah[c][2] = t2.h; al[c][2] = t2.l;
          ah[c][3] = t3.h; al[c][3] = t3.l;
          ah[c][4] = t4.h; al[c][4] = t4.l;
          ah[c][5] = t5.h; al[c][5] = t5.l;
          ah[c][6] = t6.h; al[c][6] = t6.l;
          ah[c][7] = t7.h; al[c][7] = t7.l;
        }
      }
      f32x4 acc = {0.f, 0.f, 0.f, 0.f};
#pragma unroll
      for (int c = 0; c < 2; ++c) {
        acc = __builtin_amdgcn_mfma_f32_16x16x32_f16(ah[c], wh[c], acc, 0, 0, 0);
        acc = __builtin_amdgcn_mfma_f32_16x16x32_f16(ah[c], wl[c], acc, 0, 0, 0);
        acc = __builtin_amdgcn_mfma_f32_16x16x32_f16(al[c], wh[c], acc, 0, 0, 0);
      }
#pragma unroll
      for (int r = 0; r < 4; ++r) {
        int so = mt * 16 + oct * 4 + r;
        if (so < 200) {
          HL t = split2(acc[r] + biasc);
          sth[(so - rb) * 72 + d0 + col] = t.h;
          stl[(so - rb) * 72 + d0 + col] = t.l;
        }
      }
    }
  };

  // pass 1: rows 0..127 (mt 0..7)
  compute_rows(0, 8, 0);
  __syncthreads();
#pragma unroll
  for (int t = 0; t < 4; ++t) {
#pragma unroll
    for (int j = 0; j < 8; ++j) {
      int sR = 32 * t + oct * 8 + j;
      vBh[t][j] = sth[sR * 72 + d0 + col];
      vBl[t][j] = stl[sR * 72 + d0 + col];
    }
  }
#pragma unroll
  for (int u = 0; u < 2; ++u) {
    int sR = (wv + 4 * u) * 16 + col;  // <= 127
#pragma unroll
    for (int c = 0; c < 2; ++c) {
      vCh[u][c] = *(const f16x8*)&sth[sR * 72 + 32 * c + oct * 8];
      vCl[u][c] = *(const f16x8*)&stl[sR * 72 + 32 * c + oct * 8];
    }
  }
  __syncthreads();

  // pass 2: rows 128..199 (mt 8..12)
  compute_rows(8, 13, 128);
  __syncthreads();
#pragma unroll
  for (int t = 4; t < 7; ++t) {
    if (t < 6 || oct == 0) {
#pragma unroll
      for (int j = 0; j < 8; ++j) {
        int sR = 32 * t + oct * 8 + j - 128;
        vBh[t][j] = sth[sR * 72 + d0 + col];
        vBl[t][j] = stl[sR * 72 + d0 + col];
      }
    } else {
      vBh[t] = f16x8{};
      vBl[t] = f16x8{};
    }
  }
#pragma unroll
  for (int u = 2; u < 4; ++u) {
    int mt = wv + 4 * u;
    if (mt < 13) {
      int sR = mt * 16 + col;
      if (sR > 199) sR = 199;  // dup rows feed unstored D rows only
      sR -= 128;
#pragma unroll
      for (int c = 0; c < 2; ++c) {
        vCh[u][c] = *(const f16x8*)&sth[sR * 72 + 32 * c + oct * 8];
        vCl[u][c] = *(const f16x8*)&stl[sR * 72 + 32 * c + oct * 8];
      }
    } else {
#pragma unroll
      for (int c = 0; c < 2; ++c) {
        vCh[u][c] = f16x8{};
        vCl[u][c] = f16x8{};
      }
    }
  }
  __syncthreads();

  // ---- stage b_init -> bT[k][s] fp32 (overwrites dead staging) ----
  const float* gb = gb0 + (size_t)b * 1600;
  for (int idx = tid; idx < 1600; idx += 256)
    smF[(idx & 7) * 204 + (idx >> 3)] = gb[idx];
  __syncthreads();

  // ================= routing iterations =================
#pragma unroll 1
  for (int it = 0; it < NITERS; ++it) {
    // ---- Phase A: e' = 4096*exp(b-max), N-packed [eh|el] frag layout ----
#pragma unroll
    for (int ki = 0; ki < 2; ++ki) {
      int kk = 2 * wv + ki;
      float4 bv;
      if (lane < 50)
        bv = *(const float4*)&smF[kk * 204 + 4 * lane];
      else
        bv = make_float4(-3e38f, -3e38f, -3e38f, -3e38f);
      float mx = fmaxf(fmaxf(bv.x, bv.y), fmaxf(bv.z, bv.w));
#pragma unroll
      for (int m = 1; m <= 32; m <<= 1) mx = fmaxf(mx, __shfl_xor(mx, m, 64));
      float e0 = 0.f, e1 = 0.f, e2 = 0.f, e3 = 0.f;
      if (lane < 50) {
        e0 = __expf(bv.x - mx) * 4096.f;
        e1 = __expf(bv.y - mx) * 4096.f;
        e2 = __expf(bv.z - mx) * 4096.f;
        e3 = __expf(bv.w - mx) * 4096.f;
      }
      HL s0 = split2(e0), s1 = split2(e1), s2 = split2(e2), s3 = split2(e3);
      f16x4 hv, lv;
      hv[0] = s0.h; lv[0] = s0.l;
      hv[1] = s1.h; lv[1] = s1.l;
      hv[2] = s2.h; lv[2] = s2.l;
      hv[3] = s3.h; lv[3] = s3.l;
      if (lane < 56) {  // lanes 50..55 store zeros -> tail rows stay zero
        int slot = (lane >> 1) * 136 + kk * 8 + (lane & 1) * 4;
        *(f16x4*)&smH[EF_H + slot] = hv;         // n = kk   (hi)
        *(f16x4*)&smH[EF_H + slot + 64] = lv;    // n = kk+8 (lo)
      }
      float se = ((float)hv[0] + (float)lv[0]) + ((float)hv[1] + (float)lv[1]) +
                 ((float)hv[2] + (float)lv[2]) + ((float)hv[3] + (float)lv[3]);
#pragma unroll
      for (int m = 1; m <= 32; m <<= 1) se += __shfl_xor(se, m, 64);
      if (lane == 0) smF[SE_F + kk] = se;
    }
    __syncthreads();

    // ---- Phase B: z[d][k] = v . e, packed-N (2 MFMA per K-tile) ----
    f32x4 z = {0.f, 0.f, 0.f, 0.f};
#pragma unroll
    for (int t = 0; t < 7; ++t) {
      f16x8 ep = *(const f16x8*)&smH[EF_H + (t * 4 + oct) * 136 + col * 8];
      z = __builtin_amdgcn_mfma_f32_16x16x32_f16(vBh[t], ep, z, 0, 0, 0);
      z = __builtin_amdgcn_mfma_f32_16x16x32_f16(vBl[t], ep, z, 0, 0, 0);
    }
#pragma unroll
    for (int r = 0; r < 4; ++r) z[r] += __shfl_xor(z[r], 8, 64);
    // sum of squares (for squash), reduce across d-chunks (octs)
    float sq = z[0] * z[0] + z[1] * z[1] + z[2] * z[2] + z[3] * z[3];
    sq += __shfl_xor(sq, 16, 64);
    sq += __shfl_xor(sq, 32, 64);
    if (oct == 0 && col < 8) smF[SQP_F + wv * 8 + col] = sq;
    // store zn N-packed: col<8 lanes store hi-limb, col>=8 lanes lo-limb
    {
      f16x4 st;
#pragma unroll
      for (int r = 0; r < 4; ++r) {
        float val = z[r] * (1.f / 4096.f);
        _Float16 h = (_Float16)val;
        st[r] = (col < 8) ? h : (_Float16)(val - (float)h);
      }
      int octf = (2 * wv + (oct >> 1)) & 3;
      int slot = ((wv >> 1) * 4 + octf) * 136 + col * 8 + (oct & 1) * 4;
      *(f16x4*)&smH[ZN_H + slot] = st;
    }
    __syncthreads();

    // ---- squash scalars (redundant per lane, k = kcol) ----
    float sqt = smF[SQP_F + kcol] + smF[SQP_F + 8 + kcol] +
                smF[SQP_F + 16 + kcol] + smF[SQP_F + 24 + kcol];
    float Se = smF[SE_F + kcol];
    float ns = sqt / (64.f * Se * Se);
    float g = ns / ((1.f + ns) * sqrtf(ns + 1e-9f));
    float cv = g / Se;

    if (it == NITERS - 1) {
      // final readout: u[k][d] = cv * z (z is 4096-scaled; cv absorbs it)
      if (col < 8) {
        float4 u4;
        u4.x = cv * z[0];
        u4.y = cv * z[1];
        u4.z = cv * z[2];
        u4.w = cv * z[3];
        *(float4*)&gout[(size_t)b * 512 + col * 64 + 16 * wv + 4 * oct] = u4;
      }
    } else {
      // ---- Phase C: bT[k][s] += cvC * (v . zn), packed-N ----
      float cvC = cv * 4096.f;
      f16x8 zf0 = *(const f16x8*)&smH[ZN_H + oct * 136 + col * 8];
      f16x8 zf1 = *(const f16x8*)&smH[ZN_H + (4 + oct) * 136 + col * 8];
#pragma unroll
      for (int u = 0; u < 4; ++u) {
        int mt = wv + 4 * u;
        if (mt < 13) {
          f32x4 a = {0.f, 0.f, 0.f, 0.f};
          a = __builtin_amdgcn_mfma_f32_16x16x32_f16(vCh[u][0], zf0, a, 0, 0, 0);
          a = __builtin_amdgcn_mfma_f32_16x16x32_f16(vCl[u][0], zf0, a, 0, 0, 0);
          a = __builtin_amdgcn_mfma_f32_16x16x32_f16(vCh[u][1], zf1, a, 0, 0, 0);
          a = __builtin_amdgcn_mfma_f32_16x16x32_f16(vCl[u][1], zf1, a, 0, 0, 0);
#pragma unroll
          for (int r = 0; r < 4; ++r) a[r] += __shfl_xor(a[r], 8, 64);
          if (col < 8) {
            int s0 = mt * 16 + 4 * oct;
            if (s0 < 200) {
              float* bp = &smF[col * 204 + s0];
              float4 bb = *(float4*)bp;
              bb.x += cvC * a[0];
              bb.y += cvC * a[1];
              bb.z += cvC * a[2];
              bb.w += cvC * a[3];
              *(float4*)bp = bb;
            }
          }
        }
      }
    }
    __syncthreads();
  }
}

extern "C" void kernel_launch(void* const* d_in, const int* in_sizes, int n_in,
                              void* d_out, int out_size, void* d_ws,
                              size_t ws_size, hipStream_t stream) {
  const float* gin = (const float*)d_in[0];
  const float* gW = (const float*)d_in[1];
  const float* gbias = (const float*)d_in[2];
  const float* gb0 = (const float*)d_in[3];
  float* gout = (float*)d_out;
  hipLaunchKernelGGL(mie4, dim3(2048), dim3(256), 0, stream, gin, gW, gbias,
                     gb0, gout);
}